// Round 6
// baseline (4060.095 us; speedup 1.0000x reference)
//
#include <hip/hip_runtime.h>
#include <hip/hip_bf16.h>

#define BB 256
#define TT 512
#define DD 512
#define HH 1024
#define OO 512

typedef unsigned short u16;
typedef unsigned int u32;
typedef unsigned long long u64;
typedef __attribute__((ext_vector_type(8))) short frag8;
typedef __attribute__((ext_vector_type(4))) float floatx4;

#define MFMA16 __builtin_amdgcn_mfma_f32_16x16x32_bf16
#define AL(p) __hip_atomic_load((p), __ATOMIC_RELAXED, __HIP_MEMORY_SCOPE_AGENT)
#define AS(p, v) __hip_atomic_store((p), (v), __ATOMIC_RELAXED, __HIP_MEMORY_SCOPE_AGENT)

__device__ __forceinline__ u16 f2b(float f) {
  union { float f; u32 u; } v; v.f = f;
  u32 r = v.u + 0x7fffu + ((v.u >> 16) & 1u);
  return (u16)(r >> 16);
}
__device__ __forceinline__ float b2f(u16 b) {
  union { u32 u; float f; } v; v.u = ((u32)b) << 16; return v.f;
}
__device__ __forceinline__ float fast_tanh(float x) {
  float e = __expf(2.0f * x);
  return 1.0f - 2.0f / (e + 1.0f);
}
__device__ __forceinline__ frag8 mkfrag(u64 lo, u64 hi) {
  union { u64 d[2]; frag8 f; } u; u.d[0] = lo; u.d[1] = hi; return u.f;
}
// HW packed f32->bf16 (RNE, matches f2b) -- one instr per 2 elements
__device__ __forceinline__ u32 cvtpk(float lo, float hi) {
  u32 r;
  asm("v_cvt_pk_bf16_f32 %0, %1, %2" : "=v"(r) : "v"(lo), "v"(hi));
  return r;
}
__device__ __forceinline__ frag8 cvt8(float4 a, float4 b) {
  union { u32 w[4]; frag8 f; } u;
  u.w[0] = cvtpk(a.x, a.y); u.w[1] = cvtpk(a.z, a.w);
  u.w[2] = cvtpk(b.x, b.y); u.w[3] = cvtpk(b.z, b.w);
  return u.f;
}

// transpose f32 [K][N] -> bf16 [N][K]
__global__ void k_transpose(const float* __restrict__ src, u16* __restrict__ dst,
                            int K, int N) {
  int idx = blockIdx.x * 256 + threadIdx.x;
  if (idx >= K * N) return;
  int k = idx / N, n = idx - k * N;
  dst[(u64)n * K + k] = f2b(src[idx]);
}

__global__ void k_init_s0(const float* __restrict__ h0, u16* __restrict__ S) {
  int idx = blockIdx.x * 256 + threadIdx.x;
  if (idx < BB * HH) S[idx] = f2b(h0[idx]);
}

__global__ void k_final_h(const u16* __restrict__ Sl, float* __restrict__ out) {
  int idx = blockIdx.x * 256 + threadIdx.x;
  if (idx < BB * HH) out[idx] = b2f(Sl[idx]);
}

// fill S slots 1..TT with the sentinel 0xFFFF (bf16 NaN -- tanh never emits it)
__global__ void k_fill_sent(uint4* __restrict__ p) {
  u64 i = (u64)blockIdx.x * 256 + threadIdx.x;
  p[i] = make_uint4(0xFFFFFFFFu, 0xFFFFFFFFu, 0xFFFFFFFFu, 0xFFFFFFFFu);
}

// ---------------------------------------------------------------------------
// Fused persistent scan:
//   for t in 0..TT:  S[t+1] = tanh( [S[t] | x_t] @ [W_hh ; W_xh] )
// Grid 8x32 = 256 blocks (1/CU). Block (mb,nb): rows mb*32..+32, cols
// nb*32..+32, all steps. LDS-resident: W_hh slice [32][1024] + W_xh slice
// [32][512] + double-buffered reduction scratch.
//
// v4 sync: DATA-AS-FLAG. No flags, no producer drain, no acquire fence.
//  - Producer stores h tile as sc0sc1 u32 pairs and immediately proceeds.
//  - Consumer polls its A chunks directly (relaxed sc0sc1 u64 loads); a u32
//    half equal to 0xFFFFFFFF means "not yet written" (both bf16 = NaN,
//    impossible for tanh output). The validating load IS the data load:
//    one L3 round trip replaces drain + flag-store + flag-poll + gather.
//  - x-contribution (old GEMM1) fused as extra K: wave wv covers h-k
//    [wv*256,+256) and x-k [wv*128,+128). x gathered f32 from input at loop
//    top; its latency and f2b conversion hide under the h-wait.
//  - Red double-buffered -> ONE __syncthreads per step.
// ---------------------------------------------------------------------------
__global__ __launch_bounds__(256) void k_scan(const u16* __restrict__ Whh_t,
                                              const u16* __restrict__ Wxh_t,
                                              const float* __restrict__ X,
                                              u16* __restrict__ S) {
  extern __shared__ __align__(16) u16 smem[];
  u16* Ws = smem;                                   // [32][1032] bf16 (66048 B)
  u16* Wxs = smem + 32 * 1032;                      // [32][520]  bf16 (33280 B)
  float* Red = (float*)(smem + 32 * 1032 + 32 * 520);  // [2][4][32][33] f32 (33792 B)

  const int tid = threadIdx.x;
  const int mb = blockIdx.x;   // 0..7  (row block)
  const int nb = blockIdx.y;   // 0..31 (col block)
  const int m0 = mb * 32, n0 = nb * 32;
  const int lane = tid & 63, wv = tid >> 6;
  const int fr = lane & 15, q = lane >> 4;
  const int kbase = wv * 256;    // h-K slice for this wave
  const int xkbase = wv * 128;   // x-K slice for this wave
  const int er = tid >> 4;       // 0..15 (epilogue row)
  const int ec = (tid & 15) * 2; // 0..30 (epilogue col pair)

  // Stage W_hh slice: rows n0..n0+32 of Whh_t [n][k=1024]
  {
    const u16* Wb = Whh_t + (u64)n0 * HH;
#pragma unroll
    for (int it = 0; it < 16; ++it) {
      int linear = (it * 256 + tid) * 8;
      int r = linear >> 10, c = linear & 1023;
      *(uint4*)&Ws[r * 1032 + c] = *(const uint4*)(Wb + (u64)r * HH + c);
    }
  }
  // Stage W_xh slice: rows n0..n0+32 of Wxh_t [n][k=512]
  {
    const u16* Wb = Wxh_t + (u64)n0 * DD;
#pragma unroll
    for (int it = 0; it < 8; ++it) {
      int linear = (it * 256 + tid) * 8;
      int r = linear >> 9, c = linear & 511;
      *(uint4*)&Wxs[r * 520 + c] = *(const uint4*)(Wb + (u64)r * DD + c);
    }
  }
  __syncthreads();

  for (int t = 0; t < TT; ++t) {
    // ---- 1. issue x gathers (f32, strided rows; latency hides under h-wait)
    const float* xr0 = X + ((u64)(m0 + fr) * TT + t) * DD + xkbase;
    const float* xr1 = X + ((u64)(m0 + 16 + fr) * TT + t) * DD + xkbase;
    float4 xv[16];
#pragma unroll
    for (int xkt = 0; xkt < 4; ++xkt) {
      xv[xkt * 4 + 0] = *(const float4*)(xr0 + xkt * 32 + q * 8);
      xv[xkt * 4 + 1] = *(const float4*)(xr0 + xkt * 32 + q * 8 + 4);
      xv[xkt * 4 + 2] = *(const float4*)(xr1 + xkt * 32 + q * 8);
      xv[xkt * 4 + 3] = *(const float4*)(xr1 + xkt * 32 + q * 8 + 4);
    }

    floatx4 acc[2][2];
#pragma unroll
    for (int i = 0; i < 2; ++i)
#pragma unroll
      for (int j = 0; j < 2; ++j) acc[i][j] = (floatx4){0.f, 0.f, 0.f, 0.f};

    // ---- 2. x-MFMAs (independent of h; executes while producers finish)
#pragma unroll
    for (int xkt = 0; xkt < 4; ++xkt) {
      const int k = xkbase + xkt * 32 + q * 8;
      frag8 ax0 = cvt8(xv[xkt * 4 + 0], xv[xkt * 4 + 1]);
      frag8 ax1 = cvt8(xv[xkt * 4 + 2], xv[xkt * 4 + 3]);
      frag8 b0 = *(const frag8*)&Wxs[fr * 520 + k];
      frag8 b1 = *(const frag8*)&Wxs[(16 + fr) * 520 + k];
      acc[0][0] = MFMA16(ax0, b0, acc[0][0], 0, 0, 0);
      acc[0][1] = MFMA16(ax0, b1, acc[0][1], 0, 0, 0);
      acc[1][0] = MFMA16(ax1, b0, acc[1][0], 0, 0, 0);
      acc[1][1] = MFMA16(ax1, b1, acc[1][1], 0, 0, 0);
    }

    // ---- 3. h: poll-validate-consume per k-chunk (chunk kt <-> producer
    //         block (mb, wv*8+kt) of step t-1; slot t written exactly once)
    const u16* St = S + (u64)t * BB * HH;
    const u64* A0p = (const u64*)(St + (u64)(m0 + fr) * HH + kbase + q * 8);
    const u64* A1p = (const u64*)(St + (u64)(m0 + 16 + fr) * HH + kbase + q * 8);
#pragma unroll
    for (int kt = 0; kt < 8; ++kt) {
      u64 c0, c1, c2, c3;
      for (;;) {
        c0 = AL(A0p + kt * 8);     c1 = AL(A0p + kt * 8 + 1);
        c2 = AL(A1p + kt * 8);     c3 = AL(A1p + kt * 8 + 1);
        u32 bad = ((u32)c0 == 0xFFFFFFFFu) | ((u32)(c0 >> 32) == 0xFFFFFFFFu) |
                  ((u32)c1 == 0xFFFFFFFFu) | ((u32)(c1 >> 32) == 0xFFFFFFFFu) |
                  ((u32)c2 == 0xFFFFFFFFu) | ((u32)(c2 >> 32) == 0xFFFFFFFFu) |
                  ((u32)c3 == 0xFFFFFFFFu) | ((u32)(c3 >> 32) == 0xFFFFFFFFu);
        if (!bad) break;
      }
      const int k = kbase + kt * 32 + q * 8;
      frag8 b0 = *(const frag8*)&Ws[fr * 1032 + k];
      frag8 b1 = *(const frag8*)&Ws[(16 + fr) * 1032 + k];
      frag8 af0 = mkfrag(c0, c1);
      frag8 af1 = mkfrag(c2, c3);
      acc[0][0] = MFMA16(af0, b0, acc[0][0], 0, 0, 0);
      acc[0][1] = MFMA16(af0, b1, acc[0][1], 0, 0, 0);
      acc[1][0] = MFMA16(af1, b0, acc[1][0], 0, 0, 0);
      acc[1][1] = MFMA16(af1, b1, acc[1][1], 0, 0, 0);
    }

    // ---- 4. K-split partials -> LDS (double-buffered)
    float* R = Red + (t & 1) * (4 * 32 * 33);
#pragma unroll
    for (int im = 0; im < 2; ++im)
#pragma unroll
      for (int in = 0; in < 2; ++in)
#pragma unroll
        for (int r = 0; r < 4; ++r) {
          int row = im * 16 + q * 4 + r;
          int col = in * 16 + fr;
          R[(wv * 32 + row) * 33 + col] = acc[im][in][r];
        }
    __syncthreads();  // the only barrier per step

    // ---- 5. reduce, tanh, store (sc0sc1 u32 pairs); no drain, no flag
    u16* Sout = S + (u64)(t + 1) * BB * HH + (u64)m0 * HH + n0;
    float s00 = R[(0 * 32 + er) * 33 + ec]     + R[(1 * 32 + er) * 33 + ec] +
                R[(2 * 32 + er) * 33 + ec]     + R[(3 * 32 + er) * 33 + ec];
    float s01 = R[(0 * 32 + er) * 33 + ec + 1] + R[(1 * 32 + er) * 33 + ec + 1] +
                R[(2 * 32 + er) * 33 + ec + 1] + R[(3 * 32 + er) * 33 + ec + 1];
    float s10 = R[(0 * 32 + er + 16) * 33 + ec]     + R[(1 * 32 + er + 16) * 33 + ec] +
                R[(2 * 32 + er + 16) * 33 + ec]     + R[(3 * 32 + er + 16) * 33 + ec];
    float s11 = R[(0 * 32 + er + 16) * 33 + ec + 1] + R[(1 * 32 + er + 16) * 33 + ec + 1] +
                R[(2 * 32 + er + 16) * 33 + ec + 1] + R[(3 * 32 + er + 16) * 33 + ec + 1];
    u32 p0 = cvtpk(fast_tanh(s00), fast_tanh(s01));
    u32 p1 = cvtpk(fast_tanh(s10), fast_tanh(s11));
    AS((u32*)(Sout + (u64)er * HH + ec), p0);
    AS((u32*)(Sout + (u64)(er + 16) * HH + ec), p1);
    // no trailing barrier: Red is double-buffered; consumers self-validate
  }
}

// ---------------------------------------------------------------------------
// GEMM3: Y = Hs @ W_hy.  Hs bf16 [T*B][HH] (m = t*B + b), Wt bf16 [OO][HH].
// ---------------------------------------------------------------------------
__global__ __launch_bounds__(256) void k_gemm_hy(const u16* __restrict__ Hs,
                                                 const u16* __restrict__ Wt,
                                                 float* __restrict__ out) {
  __shared__ __align__(16) u16 As[64 * 72];
  __shared__ __align__(16) u16 Bs[64 * 72];
  const int tid = threadIdx.x;
  const int m0 = blockIdx.x * 64, n0 = blockIdx.y * 64;
  const int lane = tid & 63, wv = tid >> 6;
  const int fr = lane & 15, quad = lane >> 4;

  floatx4 acc[4];
#pragma unroll
  for (int i = 0; i < 4; ++i) acc[i] = (floatx4){0.f, 0.f, 0.f, 0.f};

  for (int kc = 0; kc < HH; kc += 64) {
    const u16* Ab = Hs + (u64)m0 * HH + kc;
#pragma unroll
    for (int it = 0; it < 2; ++it) {
      int linear = (it * 256 + tid) * 8;
      int r = linear >> 6, c = linear & 63;
      *(uint4*)&As[r * 72 + c] = *(const uint4*)(Ab + (u64)r * HH + c);
    }
    const u16* Bb = Wt + (u64)n0 * HH + kc;
#pragma unroll
    for (int it = 0; it < 2; ++it) {
      int linear = (it * 256 + tid) * 8;
      int n = linear >> 6, c = linear & 63;
      *(uint4*)&Bs[n * 72 + c] = *(const uint4*)(Bb + (u64)n * HH + c);
    }
    __syncthreads();
#pragma unroll
    for (int kk = 0; kk < 64; kk += 32) {
      frag8 bf = *(const frag8*)&Bs[(wv * 16 + fr) * 72 + kk + quad * 8];
#pragma unroll
      for (int i = 0; i < 4; ++i) {
        frag8 af = *(const frag8*)&As[(i * 16 + fr) * 72 + kk + quad * 8];
        acc[i] = MFMA16(af, bf, acc[i], 0, 0, 0);
      }
    }
    __syncthreads();
  }
  const int col = n0 + wv * 16 + fr;
#pragma unroll
  for (int i = 0; i < 4; ++i) {
#pragma unroll
    for (int r = 0; r < 4; ++r) {
      int m = m0 + i * 16 + quad * 4 + r;
      int t = m >> 8;       // m / BB
      int b = m & (BB - 1); // m % BB
      out[(u64)b * (TT * OO) + (u64)t * OO + col] = acc[i][r];
    }
  }
}

extern "C" void kernel_launch(void* const* d_in, const int* in_sizes, int n_in,
                              void* d_out, int out_size, void* d_ws, size_t ws_size,
                              hipStream_t stream) {
  (void)in_sizes; (void)n_in; (void)out_size; (void)ws_size;
  const float* x    = (const float*)d_in[0];
  const float* h0   = (const float*)d_in[1];
  const float* w_xh = (const float*)d_in[2];
  const float* w_hh = (const float*)d_in[3];
  const float* w_hy = (const float*)d_in[4];
  float* out = (float*)d_out;

  // workspace layout (bf16):
  //   S     : [TT+1][BB][HH]  pure-h state (slot 0 = h0; slot t = h_t;
  //                           slots 1..TT sentinel-filled before the scan)
  //   Wxh_t : [HH][DD]
  //   Whh_t : [HH][HH]
  //   Why_t : [OO][HH]
  u16* S = (u16*)d_ws;
  u64 s_elems = (u64)(TT + 1) * BB * HH;
  u16* Wxh_t = S + s_elems;
  u16* Whh_t = Wxh_t + (u64)HH * DD;
  u16* Why_t = Whh_t + (u64)HH * HH;

  k_transpose<<<dim3((DD * HH + 255) / 256), dim3(256), 0, stream>>>(w_xh, Wxh_t, DD, HH);
  k_transpose<<<dim3((HH * HH + 255) / 256), dim3(256), 0, stream>>>(w_hh, Whh_t, HH, HH);
  k_transpose<<<dim3((HH * OO + 255) / 256), dim3(256), 0, stream>>>(w_hy, Why_t, HH, OO);
  k_init_s0<<<dim3(BB * HH / 256), dim3(256), 0, stream>>>(h0, S);

  // sentinel-fill slots 1..TT: TT*BB*HH u16 = 16,777,216 uint4 = 65536 blocks
  k_fill_sent<<<dim3(65536), dim3(256), 0, stream>>>(
      (uint4*)(S + (u64)BB * HH));

  const int scan_lds = 32 * 1032 * 2 + 32 * 520 * 2 + 2 * 4 * 32 * 33 * 4;  // 133120 B
  hipFuncSetAttribute((const void*)k_scan,
                      hipFuncAttributeMaxDynamicSharedMemorySize, scan_lds);
  k_scan<<<dim3(8, 32), dim3(256), scan_lds, stream>>>(Whh_t, Wxh_t, x, S);

  k_gemm_hy<<<dim3((TT * BB) / 64, OO / 64), dim3(256), 0, stream>>>(
      S + (u64)BB * HH, Why_t, out);
  k_final_h<<<dim3(BB * HH / 256), dim3(256), 0, stream>>>(
      S + (u64)TT * BB * HH, out + (u64)BB * TT * OO);
}